// Round 7
// baseline (805.131 us; speedup 1.0000x reference)
//
#include <hip/hip_runtime.h>

#define THRESH 0.1f

typedef float    f4 __attribute__((ext_vector_type(4)));
typedef float    f2 __attribute__((ext_vector_type(2)));
typedef _Float16 h8 __attribute__((ext_vector_type(8)));
typedef _Float16 h4 __attribute__((ext_vector_type(4)));
typedef _Float16 h2 __attribute__((ext_vector_type(2)));

// ---------------------------------------------------------------------------
// Merged weight norm (per-row reduction math identical to all prior rounds).
// Linear rows are written PERMUTED to HWC fanin order: dst[pix*64+c]=src[c*16+pix]
// ---------------------------------------------------------------------------
__global__ void wnorm_all(const float* __restrict__ c0v, const float* __restrict__ c0g,
                          const float* __restrict__ c1v, const float* __restrict__ c1g,
                          const float* __restrict__ c2v, const float* __restrict__ c2g,
                          const float* __restrict__ c3v, const float* __restrict__ c3g,
                          const float* __restrict__ lv,  const float* __restrict__ lg,
                          float* __restrict__ w0, float* __restrict__ w1,
                          float* __restrict__ w2, float* __restrict__ w3,
                          float* __restrict__ wl) {
    int rb = blockIdx.x;
    const float *v, *g; float* w; int fanin, row;
    if (rb < 8)        { v = c0v; g = c0g; w = w0; fanin = 18;   row = rb; }
    else if (rb < 24)  { v = c1v; g = c1g; w = w1; fanin = 72;   row = rb - 8; }
    else if (rb < 56)  { v = c2v; g = c2g; w = w2; fanin = 144;  row = rb - 24; }
    else if (rb < 120) { v = c3v; g = c3g; w = w3; fanin = 288;  row = rb - 56; }
    else               { v = lv;  g = lg;  w = wl; fanin = 1024; row = rb - 120; }
    const bool perm = (rb >= 120);

    const float* vr = v + (size_t)row * fanin;
    float ss = 0.f;
    for (int i = threadIdx.x; i < fanin; i += 64) { float x = vr[i]; ss = fmaf(x, x, ss); }
    #pragma unroll
    for (int off = 32; off > 0; off >>= 1) ss += __shfl_down(ss, off);
    ss = __shfl(ss, 0);
    float scale = g[row] / sqrtf(ss);
    float* wr = w + (size_t)row * fanin;
    for (int i = threadIdx.x; i < fanin; i += 64) {
        int d = perm ? (((i & 15) << 6) | (i >> 4)) : i;
        wr[d] = vr[i] * scale;
    }
}

// ---------------------------------------------------------------------------
// Fused conv3x3(SAME) + IAF + 2x2 avgpool.  f16/HWC inter-layer tensors.
// R10: L2/L3 CG doubled (halved LDS read traffic).
// R11/R13 (failed): TP=2 full unroll needs ~290 live VGPRs; the 256 addressable
//   VGPR cap is ARCHITECTURAL -> scratch spills regardless of launch_bounds.
// R12 (failed): rolled o-loop -> loop boundary = scheduling fence, reads of
//   o+1 serialized after fmas of o (VALUBusy 31%).
// R14: 2-stage software pipeline with sched_barrier(0)-pinned schedule:
//   L(0); L(1); [SB] F(0) [SB]; L(2); [SB] F(1) [SB]; ... ; F(last).
//   Live set = 2 stages x 18 h8 = 144 VGPR (fits); stage o+1's ds_reads are
//   in flight under F(o)'s fma issue (compiler emits partial lgkmcnt).
//   Per-chain fma order (o,cid,k asc) forced by acc dependencies -> bit-exact.
// ---------------------------------------------------------------------------
template<int CIN, int H, int COUT, int CG, int WX, int SEGS, int BDIM, int PSB, int TP, int MINW>
__launch_bounds__(BDIM, MINW)
__global__ void conv_iaf_pool(const void* __restrict__ in_, const float* __restrict__ w,
                              _Float16* __restrict__ out, int B, int T) {
    constexpr bool HIN  = (CIN % 8 == 0);     // f16 HWC input path
    constexpr int Hp    = H / 2;
    constexpr int PP    = Hp * Hp;
    constexpr int HH    = H * H;
    constexpr int WY    = 64 / WX;
    constexpr int NW    = BDIM / 64;
    constexpr int NWps  = NW / SEGS;
    constexpr int XW    = H / WX;             // waves across x (L0: 2, else 1)
    constexpr int YWV   = NWps / XW;
    constexpr int RPB   = YWV * WY;           // conv rows per block
    constexpr int STRIPS= H / RPB;
    constexpr int CGRP  = COUT / (CG * SEGS);
    constexpr int SR    = RPB + 2;
    constexpr int COLS  = H + 2;
    constexpr int SLABB = SR * COLS * PSB;    // slab bytes
    constexpr bool FULLY= (RPB == H);
    constexpr int R0    = FULLY ? 1 : 0;
    constexpr int NR    = FULLY ? H : SR;
    constexpr int UPC   = HIN ? (CIN / 8) : 1;    // staging units per position
    constexpr int NU    = NR * H * UPC;
    constexpr int ITERS = (NU + BDIM - 1) / BDIM;
    constexpr bool GUARD= !(FULLY && (NU % BDIM == 0));

    __shared__ alignas(16) char slab[2 * TP][SLABB];

    const int tid = threadIdx.x;
    const int G = gridDim.x, bx = blockIdx.x;
    const int pb = (bx & 7) * (G >> 3) + (bx >> 3);   // XCD clustering
    const int cgb   = pb % CGRP;
    const int strip = (pb / CGRP) % STRIPS;
    const int b     = pb / (CGRP * STRIPS);

    const int wid = tid >> 6, l = tid & 63;
    const int seg = wid / NWps;
    const int wlv = wid % NWps;
    const int xw = wlv % XW, yw = wlv / XW;
    const int xl = l % WX, ylw = l / WX;
    const int x  = xw * WX + xl;
    const int yy = yw * WY + ylw;
    const int y0 = strip * RPB;
    const int y  = y0 + yy;

    const int c0 = __builtin_amdgcn_readfirstlane((cgb * SEGS + seg) * CG);
    const float* __restrict__ wu = w + (size_t)c0 * (CIN * 9);

    // patch base byte offsets
    int addrB[9];
    #pragma unroll
    for (int dr = 0; dr < 3; ++dr)
        #pragma unroll
        for (int dc = 0; dc < 3; ++dc)
            addrB[dr * 3 + dc] = ((yy + dr) * COLS + (x + dc)) * PSB;

    // staging maps (lane-invariant over t)
    int goff[ITERS], loffB[ITERS];
    #pragma unroll
    for (int i = 0; i < ITERS; ++i) {
        const int idx = tid + i * BDIM;
        int j, gx, rr0;
        if constexpr (HIN) { j = idx % UPC; gx = (idx / UPC) % H; rr0 = idx / (UPC * H); }
        else               { j = 0;         gx = idx % H;         rr0 = (idx / H) % NR; }
        const int rr = R0 + rr0;
        const int gy = y0 - 1 + rr;
        const bool ok = (idx < NU) && ((unsigned)gy < (unsigned)H);
        if constexpr (HIN) goff[i] = ok ? ((gy * H + gx) * UPC + j) : -1;
        else               goff[i] = ok ? (gy * H + gx) : -1;
        loffB[i] = ok ? ((rr * COLS + (gx + 1)) * PSB + 16 * j) : -1;
    }

    constexpr bool WREG = !HIN && (CG * CIN * 9) <= 80;   // L0 only
    float wreg[WREG ? (CG * CIN * 9) : 1];
    if constexpr (WREG) {
        #pragma unroll
        for (int i = 0; i < CG * CIN * 9; ++i) wreg[i] = wu[i];
    }

    // zero all slabs (halo rows/cols persist as zeros)
    for (int i = tid; i < (2 * TP * SLABB) / 4; i += BDIM) ((int*)slab)[i] = 0;
    __syncthreads();

    float vmem[CG];
    #pragma unroll
    for (int c = 0; c < CG; ++c) vmem[c] = 0.f;

    f4 pf[TP][ITERS];
    #define GATHER(ph, t_)                                                        \
        if constexpr (HIN) {                                                      \
            const f4* inb = (const f4*)in_ + (size_t)(b * T + (t_)) * (HH * UPC); \
            _Pragma("unroll")                                                     \
            for (int i = 0; i < ITERS; ++i) {                                     \
                f4 r_ = {0.f, 0.f, 0.f, 0.f};                                     \
                if (!GUARD || goff[i] >= 0) r_ = inb[goff[i]];                    \
                pf[ph][i] = r_;                                                   \
            }                                                                     \
        } else {                                                                  \
            const float* inb = (const float*)in_ + (size_t)(b * T + (t_)) * (CIN * HH); \
            _Pragma("unroll")                                                     \
            for (int i = 0; i < ITERS; ++i) {                                     \
                f4 r_ = {0.f, 0.f, 0.f, 0.f};                                     \
                if (goff[i] >= 0) { r_.x = inb[goff[i]]; r_.y = inb[goff[i] + HH]; } \
                pf[ph][i] = r_;                                                   \
            }                                                                     \
        }
    #define STAGE(buf, ph)                                                        \
        _Pragma("unroll")                                                         \
        for (int i = 0; i < ITERS; ++i) {                                         \
            if (!GUARD || loffB[i] >= 0) {                                        \
                if constexpr (HIN) *(f4*)(&slab[buf][loffB[i]]) = pf[ph][i];      \
                else { f2 v2_; v2_.x = pf[ph][i].x; v2_.y = pf[ph][i].y;          \
                       *(f2*)(&slab[buf][loffB[i]]) = v2_; }                      \
            }                                                                     \
        }

    // single-frame conv (TP=1 path)
    auto conv1 = [&](const char* sb, float* acc) {
        #pragma unroll
        for (int c = 0; c < CG; ++c) acc[c] = 0.f;
        if constexpr (HIN) {
            #pragma unroll
            for (int o = 0; o < CIN / 8; ++o) {
                h8 P[9];
                #pragma unroll
                for (int k = 0; k < 9; ++k)
                    P[k] = *(const h8*)(sb + addrB[k] + 16 * o);
                #pragma unroll
                for (int cid = 0; cid < 8; ++cid) {
                    const int ci = 8 * o + cid;
                    #pragma unroll
                    for (int c = 0; c < CG; ++c)
                        #pragma unroll
                        for (int k = 0; k < 9; ++k)
                            acc[c] = fmaf((float)P[k][cid],
                                          wu[(size_t)(c * CIN + ci) * 9 + k], acc[c]);
                }
            }
        } else {
            f2 P[9];
            #pragma unroll
            for (int k = 0; k < 9; ++k)
                P[k] = *(const f2*)(sb + addrB[k]);
            #pragma unroll
            for (int cid = 0; cid < 2; ++cid)
                #pragma unroll
                for (int c = 0; c < CG; ++c)
                    #pragma unroll
                    for (int k = 0; k < 9; ++k)
                        acc[c] = fmaf(P[k][cid],
                                      WREG ? wreg[(c * CIN + cid) * 9 + k]
                                           : wu[(size_t)(c * CIN + cid) * 9 + k],
                                      acc[c]);
        }
    };

    // dual-frame conv (TP=2 path): 2-stage software pipeline, schedule pinned
    // by sched_barrier(0). Live patch set = 2 stages x 18 h8 = 144 VGPR.
    // Stage o+1's ds_reads fly under F(o)'s fma issue. Per-chain fma order
    // (o,cid,k asc) forced by acc dependencies -> bit-exact.
    auto conv2 = [&](const char* sbA, const char* sbB, float* accA, float* accB) {
        #pragma unroll
        for (int c = 0; c < CG; ++c) { accA[c] = 0.f; accB[c] = 0.f; }
        if constexpr (HIN) {
            constexpr int NO = CIN / 8;
            h8 P[2][2][9];                       // [stage][frame][tap]
            #pragma unroll
            for (int k = 0; k < 9; ++k) {        // load stage 0 (o = 0)
                P[0][0][k] = *(const h8*)(sbA + addrB[k]);
                P[0][1][k] = *(const h8*)(sbB + addrB[k]);
            }
            #pragma unroll
            for (int o = 0; o < NO; ++o) {
                const int cur = o & 1, nxt = cur ^ 1;    // compile-time (unrolled)
                if (o + 1 < NO) {
                    #pragma unroll
                    for (int k = 0; k < 9; ++k) {        // prefetch stage o+1
                        P[nxt][0][k] = *(const h8*)(sbA + addrB[k] + 16 * (o + 1));
                        P[nxt][1][k] = *(const h8*)(sbB + addrB[k] + 16 * (o + 1));
                    }
                }
                __builtin_amdgcn_sched_barrier(0);       // pin: loads above, fmas below
                #pragma unroll
                for (int cid = 0; cid < 8; ++cid) {
                    const int ci = 8 * o + cid;
                    #pragma unroll
                    for (int c = 0; c < CG; ++c)
                        #pragma unroll
                        for (int k = 0; k < 9; ++k) {
                            const float wv = wu[(size_t)(c * CIN + ci) * 9 + k];
                            accA[c] = fmaf((float)P[cur][0][k][cid], wv, accA[c]);
                            accB[c] = fmaf((float)P[cur][1][k][cid], wv, accB[c]);
                        }
                }
                __builtin_amdgcn_sched_barrier(0);       // pin: next loads stay below
            }
        }
    };

    auto fire = [&](float* acc, int t_) {
        float sv[CG];
        #pragma unroll
        for (int c = 0; c < CG; ++c) {
            vmem[c] += acc[c];
            float s = (vmem[c] >= THRESH) ? 1.f : 0.f;
            vmem[c] -= THRESH * s;
            float sum = s;                         // exact 0/1 sums
            sum += __shfl_xor(sum, 1);
            sum += __shfl_xor(sum, WX);
            sv[c] = 0.25f * sum;                   // in {0,.25,.5,.75,1} -- exact f16
        }
        if (((xl | ylw) & 1) == 0) {
            const size_t ob = ((size_t)(b * T + t_) * PP + (y >> 1) * Hp + (x >> 1)) * COUT + c0;
            if constexpr (CG == 4) {
                h4 hv = {(_Float16)sv[0], (_Float16)sv[1], (_Float16)sv[2], (_Float16)sv[3]};
                *(h4*)(out + ob) = hv;
            } else if constexpr (CG == 2) {
                h2 hv = {(_Float16)sv[0], (_Float16)sv[1]};
                *(h2*)(out + ob) = hv;
            } else {
                out[ob] = (_Float16)sv[0];
            }
        }
    };

    if constexpr (TP == 1) {
        {   // prologue: stage frame 0, prefetch frame 1
            GATHER(0, 0)
            STAGE(0, 0)
            GATHER(0, 1)
        }
        __syncthreads();
        for (int t = 0; t < T; ++t) {
            if (t + 1 < T) { STAGE((t + 1) & 1, 0) }
            if (t + 2 < T) { GATHER(0, t + 2) }
            float acc[CG];
            conv1(slab[t & 1], acc);
            fire(acc, t);
            __syncthreads();                       // single barrier per timestep
        }
    } else {
        {   // prologue: stage frames 0,1 into slabs 0,1; prefetch frames 2,3
            GATHER(0, 0)
            GATHER(1, 1)
            STAGE(0, 0)
            STAGE(1, 1)
            GATHER(0, 2)
            GATHER(1, 3)
        }
        __syncthreads();
        for (int tt = 0; tt < T; tt += 2) {        // T even
            const int p = (tt >> 1) & 1;           // current pair slabs: 2p, 2p+1
            if (tt + 2 < T) { STAGE(2 * (p ^ 1), 0) STAGE(2 * (p ^ 1) + 1, 1) }
            if (tt + 4 < T) { GATHER(0, tt + 4) GATHER(1, tt + 5) }
            float accA[CG], accB[CG];
            conv2(&slab[2 * p][0], &slab[2 * p + 1][0], accA, accB);
            fire(accA, tt);
            fire(accB, tt + 1);
            __syncthreads();                       // single barrier per PAIR
        }
    }
    #undef GATHER
    #undef STAGE
}

// ---------------------------------------------------------------------------
// Linear: out (1600, 11) = h (1600, 1024 f16 HWC) @ wl_perm^T (11, 1024)
// ---------------------------------------------------------------------------
__global__ void linear_kernel(const _Float16* __restrict__ h, const float* __restrict__ w,
                              float* __restrict__ out) {
    __shared__ float hs[1024];
    __shared__ float part[16][17];
    const int n = blockIdx.x;
    for (int i = threadIdx.x; i < 1024; i += blockDim.x)
        hs[i] = (float)h[(size_t)n * 1024 + i];
    __syncthreads();
    const int j = threadIdx.x & 15, ch = threadIdx.x >> 4;
    float acc = 0.f;
    if (j < 11) {
        const float* wr = w + (size_t)j * 1024 + ch * 64;
        const float* hh = hs + ch * 64;
        #pragma unroll 8
        for (int k = 0; k < 64; ++k) acc = fmaf(hh[k], wr[k], acc);
    }
    part[j][ch] = acc;
    __syncthreads();
    if (threadIdx.x < 11) {
        float s = 0.f;
        #pragma unroll
        for (int cc = 0; cc < 16; ++cc) s += part[threadIdx.x][cc];
        out[(size_t)n * 11 + threadIdx.x] = s;
    }
}

// ---------------------------------------------------------------------------
extern "C" void kernel_launch(void* const* d_in, const int* in_sizes, int n_in,
                              void* d_out, int out_size, void* d_ws, size_t ws_size,
                              hipStream_t stream) {
    const int B = 32, T = 50;

    const float* x   = (const float*)d_in[0];
    const float* c0v = (const float*)d_in[1];
    const float* c0g = (const float*)d_in[2];
    const float* c1v = (const float*)d_in[3];
    const float* c1g = (const float*)d_in[4];
    const float* c2v = (const float*)d_in[5];
    const float* c2g = (const float*)d_in[6];
    const float* c3v = (const float*)d_in[7];
    const float* c3g = (const float*)d_in[8];
    const float* lv  = (const float*)d_in[9];
    const float* lg  = (const float*)d_in[10];
    float* out = (float*)d_out;

    // Workspace layout
    float* ws = (float*)d_ws;
    float* w0 = ws;                    // 8*2*9     = 144
    float* w1 = w0 + 144;              // 16*8*9    = 1152
    float* w2 = w1 + 1152;             // 32*16*9   = 4608
    float* w3 = w2 + 4608;             // 64*32*9   = 18432
    float* wl = w3 + 18432;            // 11*1024   = 11264 (HWC-permuted)
    _Float16* bufA16 = (_Float16*)(ws + 40960);            // L0 out f16 HWC
    _Float16* bufB16 = (_Float16*)(ws + 40960 + 13107200); // L1 out f16 HWC
    // L2 out reuses bufA16; L3 out reuses bufB16.

    wnorm_all<<<131, 64, 0, stream>>>(c0v, c0g, c1v, c1g, c2v, c2g, c3v, c3g,
                                      lv, lg, w0, w1, w2, w3, wl);

    // <CIN,H,COUT,CG,WX,SEGS,BDIM,PSB,TP,MINW>  grid = B * CGRP * STRIPS
    conv_iaf_pool<2,  64, 8,  4, 32, 1, 256, 8 , 1, 4><<<1024, 256, 0, stream>>>(x,       w0, bufA16, B, T); // L0
    conv_iaf_pool<8,  32, 16, 4, 32, 1, 256, 16, 1, 2><<<512,  256, 0, stream>>>(bufA16,  w1, bufB16, B, T); // L1
    conv_iaf_pool<16, 16, 32, 4, 16, 1, 256, 48, 2, 1><<<256,  256, 0, stream>>>(bufB16,  w2, bufA16, B, T); // L2 TP=2 pipelined
    conv_iaf_pool<32, 8,  64, 2, 8,  2, 128, 80, 2, 1><<<512,  128, 0, stream>>>(bufA16,  w3, bufB16, B, T); // L3 TP=2 pipelined

    linear_kernel<<<B * T, 256, 0, stream>>>(bufB16, wl, out);
}

// Round 8
// 632.641 us; speedup vs baseline: 1.2726x; 1.2726x over previous
//
#include <hip/hip_runtime.h>

#define THRESH 0.1f

typedef float    f4 __attribute__((ext_vector_type(4)));
typedef float    f2 __attribute__((ext_vector_type(2)));
typedef _Float16 h8 __attribute__((ext_vector_type(8)));
typedef _Float16 h4 __attribute__((ext_vector_type(4)));
typedef _Float16 h2 __attribute__((ext_vector_type(2)));

// ---------------------------------------------------------------------------
// Merged weight norm (per-row reduction math identical to all prior rounds).
// Linear rows are written PERMUTED to HWC fanin order: dst[pix*64+c]=src[c*16+pix]
// ---------------------------------------------------------------------------
__global__ void wnorm_all(const float* __restrict__ c0v, const float* __restrict__ c0g,
                          const float* __restrict__ c1v, const float* __restrict__ c1g,
                          const float* __restrict__ c2v, const float* __restrict__ c2g,
                          const float* __restrict__ c3v, const float* __restrict__ c3g,
                          const float* __restrict__ lv,  const float* __restrict__ lg,
                          float* __restrict__ w0, float* __restrict__ w1,
                          float* __restrict__ w2, float* __restrict__ w3,
                          float* __restrict__ wl) {
    int rb = blockIdx.x;
    const float *v, *g; float* w; int fanin, row;
    if (rb < 8)        { v = c0v; g = c0g; w = w0; fanin = 18;   row = rb; }
    else if (rb < 24)  { v = c1v; g = c1g; w = w1; fanin = 72;   row = rb - 8; }
    else if (rb < 56)  { v = c2v; g = c2g; w = w2; fanin = 144;  row = rb - 24; }
    else if (rb < 120) { v = c3v; g = c3g; w = w3; fanin = 288;  row = rb - 56; }
    else               { v = lv;  g = lg;  w = wl; fanin = 1024; row = rb - 120; }
    const bool perm = (rb >= 120);

    const float* vr = v + (size_t)row * fanin;
    float ss = 0.f;
    for (int i = threadIdx.x; i < fanin; i += 64) { float x = vr[i]; ss = fmaf(x, x, ss); }
    #pragma unroll
    for (int off = 32; off > 0; off >>= 1) ss += __shfl_down(ss, off);
    ss = __shfl(ss, 0);
    float scale = g[row] / sqrtf(ss);
    float* wr = w + (size_t)row * fanin;
    for (int i = threadIdx.x; i < fanin; i += 64) {
        int d = perm ? (((i & 15) << 6) | (i >> 4)) : i;
        wr[d] = vr[i] * scale;
    }
}

// ---------------------------------------------------------------------------
// Fused conv3x3(SAME) + IAF + 2x2 avgpool.  f16/HWC inter-layer tensors.
// R10 (best, 451.7us): L2/L3 CG doubled (halved LDS read traffic).
// R11/R13/R14 (failed): all TP=2 variants need >=2x18 h8 live -> hit the 256
//   addressable-VGPR cap -> scratch spills. Two-frame ILP abandoned.
// R15: TP=1 + FULL READ HOIST. All NO*9 ds_read_b128 of the frame are issued
//   before the fma block (sched_barrier(0) pins the split). Live set for L3 =
//   36 h8 = 144 VGPR + overhead ~= 200 < 256: fits. Reads stream through the
//   LDS pipe back-to-back; fmas for o=0 start when its 9 loads land
//   (compiler emits incremental lgkmcnt), the rest complete under the
//   ~1700-cycle fma block. Pure load reorder, same addresses, same fma chain
//   (o,cid,k asc) -> bit-exact vs R10.
// ---------------------------------------------------------------------------
template<int CIN, int H, int COUT, int CG, int WX, int SEGS, int BDIM, int PSB>
__launch_bounds__(BDIM)
__global__ void conv_iaf_pool(const void* __restrict__ in_, const float* __restrict__ w,
                              _Float16* __restrict__ out, int B, int T) {
    constexpr bool HIN  = (CIN % 8 == 0);     // f16 HWC input path
    constexpr int Hp    = H / 2;
    constexpr int PP    = Hp * Hp;
    constexpr int HH    = H * H;
    constexpr int WY    = 64 / WX;
    constexpr int NW    = BDIM / 64;
    constexpr int NWps  = NW / SEGS;
    constexpr int XW    = H / WX;             // waves across x (L0: 2, else 1)
    constexpr int YWV   = NWps / XW;
    constexpr int RPB   = YWV * WY;           // conv rows per block
    constexpr int STRIPS= H / RPB;
    constexpr int CGRP  = COUT / (CG * SEGS);
    constexpr int SR    = RPB + 2;
    constexpr int COLS  = H + 2;
    constexpr int SLABB = SR * COLS * PSB;    // slab bytes
    constexpr bool FULLY= (RPB == H);
    constexpr int R0    = FULLY ? 1 : 0;
    constexpr int NR    = FULLY ? H : SR;
    constexpr int UPC   = HIN ? (CIN / 8) : 1;    // staging units per position
    constexpr int NU    = NR * H * UPC;
    constexpr int ITERS = (NU + BDIM - 1) / BDIM;
    constexpr bool GUARD= !(FULLY && (NU % BDIM == 0));

    __shared__ alignas(16) char slab[2][SLABB];

    const int tid = threadIdx.x;
    const int G = gridDim.x, bx = blockIdx.x;
    const int pb = (bx & 7) * (G >> 3) + (bx >> 3);   // XCD clustering
    const int cgb   = pb % CGRP;
    const int strip = (pb / CGRP) % STRIPS;
    const int b     = pb / (CGRP * STRIPS);

    const int wid = tid >> 6, l = tid & 63;
    const int seg = wid / NWps;
    const int wlv = wid % NWps;
    const int xw = wlv % XW, yw = wlv / XW;
    const int xl = l % WX, ylw = l / WX;
    const int x  = xw * WX + xl;
    const int yy = yw * WY + ylw;
    const int y0 = strip * RPB;
    const int y  = y0 + yy;

    const int c0 = __builtin_amdgcn_readfirstlane((cgb * SEGS + seg) * CG);
    const float* __restrict__ wu = w + (size_t)c0 * (CIN * 9);

    // patch base byte offsets
    int addrB[9];
    #pragma unroll
    for (int dr = 0; dr < 3; ++dr)
        #pragma unroll
        for (int dc = 0; dc < 3; ++dc)
            addrB[dr * 3 + dc] = ((yy + dr) * COLS + (x + dc)) * PSB;

    // staging maps (lane-invariant over t)
    int goff[ITERS], loffB[ITERS];
    #pragma unroll
    for (int i = 0; i < ITERS; ++i) {
        const int idx = tid + i * BDIM;
        int j, gx, rr0;
        if constexpr (HIN) { j = idx % UPC; gx = (idx / UPC) % H; rr0 = idx / (UPC * H); }
        else               { j = 0;         gx = idx % H;         rr0 = (idx / H) % NR; }
        const int rr = R0 + rr0;
        const int gy = y0 - 1 + rr;
        const bool ok = (idx < NU) && ((unsigned)gy < (unsigned)H);
        if constexpr (HIN) goff[i] = ok ? ((gy * H + gx) * UPC + j) : -1;
        else               goff[i] = ok ? (gy * H + gx) : -1;
        loffB[i] = ok ? ((rr * COLS + (gx + 1)) * PSB + 16 * j) : -1;
    }

    constexpr bool WREG = !HIN && (CG * CIN * 9) <= 80;   // L0 only
    float wreg[WREG ? (CG * CIN * 9) : 1];
    if constexpr (WREG) {
        #pragma unroll
        for (int i = 0; i < CG * CIN * 9; ++i) wreg[i] = wu[i];
    }

    // zero both slabs (halo rows/cols persist as zeros)
    for (int i = tid; i < (2 * SLABB) / 4; i += BDIM) ((int*)slab)[i] = 0;
    __syncthreads();

    float vmem[CG];
    #pragma unroll
    for (int c = 0; c < CG; ++c) vmem[c] = 0.f;

    f4 pf[ITERS];
    #define GATHER(t_)                                                            \
        if constexpr (HIN) {                                                      \
            const f4* inb = (const f4*)in_ + (size_t)(b * T + (t_)) * (HH * UPC); \
            _Pragma("unroll")                                                     \
            for (int i = 0; i < ITERS; ++i) {                                     \
                f4 r_ = {0.f, 0.f, 0.f, 0.f};                                     \
                if (!GUARD || goff[i] >= 0) r_ = inb[goff[i]];                    \
                pf[i] = r_;                                                       \
            }                                                                     \
        } else {                                                                  \
            const float* inb = (const float*)in_ + (size_t)(b * T + (t_)) * (CIN * HH); \
            _Pragma("unroll")                                                     \
            for (int i = 0; i < ITERS; ++i) {                                     \
                f4 r_ = {0.f, 0.f, 0.f, 0.f};                                     \
                if (goff[i] >= 0) { r_.x = inb[goff[i]]; r_.y = inb[goff[i] + HH]; } \
                pf[i] = r_;                                                       \
            }                                                                     \
        }
    #define STAGE(buf)                                                            \
        _Pragma("unroll")                                                         \
        for (int i = 0; i < ITERS; ++i) {                                         \
            if (!GUARD || loffB[i] >= 0) {                                        \
                if constexpr (HIN) *(f4*)(&slab[buf][loffB[i]]) = pf[i];          \
                else { f2 v2_; v2_.x = pf[i].x; v2_.y = pf[i].y;                  \
                       *(f2*)(&slab[buf][loffB[i]]) = v2_; }                      \
            }                                                                     \
        }

    {   // prologue: stage frame 0, prefetch frame 1
        GATHER(0)
        STAGE(0)
        GATHER(1)
    }
    __syncthreads();

    for (int t = 0; t < T; ++t) {
        if (t + 1 < T) { STAGE((t + 1) & 1) }
        if (t + 2 < T) { GATHER(t + 2) }

        const char* sb = slab[t & 1];
        float acc[CG];
        #pragma unroll
        for (int c = 0; c < CG; ++c) acc[c] = 0.f;

        if constexpr (HIN) {
            constexpr int NO = CIN / 8;
            // R15: hoist ALL reads of this frame ahead of the fma block.
            h8 P[NO][9];
            #pragma unroll
            for (int o = 0; o < NO; ++o)
                #pragma unroll
                for (int k = 0; k < 9; ++k)
                    P[o][k] = *(const h8*)(sb + addrB[k] + 16 * o);
            __builtin_amdgcn_sched_barrier(0);   // loads above, fmas below
            #pragma unroll
            for (int o = 0; o < NO; ++o) {
                #pragma unroll
                for (int cid = 0; cid < 8; ++cid) {
                    const int ci = 8 * o + cid;
                    #pragma unroll
                    for (int c = 0; c < CG; ++c)
                        #pragma unroll
                        for (int k = 0; k < 9; ++k)
                            acc[c] = fmaf((float)P[o][k][cid],
                                          wu[(size_t)(c * CIN + ci) * 9 + k], acc[c]);
                }
            }
        } else {
            f2 P[9];
            #pragma unroll
            for (int k = 0; k < 9; ++k)
                P[k] = *(const f2*)(sb + addrB[k]);
            #pragma unroll
            for (int cid = 0; cid < 2; ++cid)
                #pragma unroll
                for (int c = 0; c < CG; ++c)
                    #pragma unroll
                    for (int k = 0; k < 9; ++k)
                        acc[c] = fmaf(P[k][cid],
                                      WREG ? wreg[(c * CIN + cid) * 9 + k]
                                           : wu[(size_t)(c * CIN + cid) * 9 + k],
                                      acc[c]);
        }

        float sv[CG];
        #pragma unroll
        for (int c = 0; c < CG; ++c) {
            vmem[c] += acc[c];
            float s = (vmem[c] >= THRESH) ? 1.f : 0.f;
            vmem[c] -= THRESH * s;
            float sum = s;                         // exact 0/1 sums
            sum += __shfl_xor(sum, 1);
            sum += __shfl_xor(sum, WX);
            sv[c] = 0.25f * sum;                   // in {0,.25,.5,.75,1} -- exact f16
        }
        if (((xl | ylw) & 1) == 0) {
            const size_t ob = ((size_t)(b * T + t) * PP + (y >> 1) * Hp + (x >> 1)) * COUT + c0;
            if constexpr (CG == 4) {
                h4 hv = {(_Float16)sv[0], (_Float16)sv[1], (_Float16)sv[2], (_Float16)sv[3]};
                *(h4*)(out + ob) = hv;
            } else if constexpr (CG == 2) {
                h2 hv = {(_Float16)sv[0], (_Float16)sv[1]};
                *(h2*)(out + ob) = hv;
            } else {
                out[ob] = (_Float16)sv[0];
            }
        }
        __syncthreads();                           // single barrier per timestep
    }
    #undef GATHER
    #undef STAGE
}

// ---------------------------------------------------------------------------
// Linear: out (1600, 11) = h (1600, 1024 f16 HWC) @ wl_perm^T (11, 1024)
// ---------------------------------------------------------------------------
__global__ void linear_kernel(const _Float16* __restrict__ h, const float* __restrict__ w,
                              float* __restrict__ out) {
    __shared__ float hs[1024];
    __shared__ float part[16][17];
    const int n = blockIdx.x;
    for (int i = threadIdx.x; i < 1024; i += blockDim.x)
        hs[i] = (float)h[(size_t)n * 1024 + i];
    __syncthreads();
    const int j = threadIdx.x & 15, ch = threadIdx.x >> 4;
    float acc = 0.f;
    if (j < 11) {
        const float* wr = w + (size_t)j * 1024 + ch * 64;
        const float* hh = hs + ch * 64;
        #pragma unroll 8
        for (int k = 0; k < 64; ++k) acc = fmaf(hh[k], wr[k], acc);
    }
    part[j][ch] = acc;
    __syncthreads();
    if (threadIdx.x < 11) {
        float s = 0.f;
        #pragma unroll
        for (int cc = 0; cc < 16; ++cc) s += part[threadIdx.x][cc];
        out[(size_t)n * 11 + threadIdx.x] = s;
    }
}

// ---------------------------------------------------------------------------
extern "C" void kernel_launch(void* const* d_in, const int* in_sizes, int n_in,
                              void* d_out, int out_size, void* d_ws, size_t ws_size,
                              hipStream_t stream) {
    const int B = 32, T = 50;

    const float* x   = (const float*)d_in[0];
    const float* c0v = (const float*)d_in[1];
    const float* c0g = (const float*)d_in[2];
    const float* c1v = (const float*)d_in[3];
    const float* c1g = (const float*)d_in[4];
    const float* c2v = (const float*)d_in[5];
    const float* c2g = (const float*)d_in[6];
    const float* c3v = (const float*)d_in[7];
    const float* c3g = (const float*)d_in[8];
    const float* lv  = (const float*)d_in[9];
    const float* lg  = (const float*)d_in[10];
    float* out = (float*)d_out;

    // Workspace layout
    float* ws = (float*)d_ws;
    float* w0 = ws;                    // 8*2*9     = 144
    float* w1 = w0 + 144;              // 16*8*9    = 1152
    float* w2 = w1 + 1152;             // 32*16*9   = 4608
    float* w3 = w2 + 4608;             // 64*32*9   = 18432
    float* wl = w3 + 18432;            // 11*1024   = 11264 (HWC-permuted)
    _Float16* bufA16 = (_Float16*)(ws + 40960);            // L0 out f16 HWC
    _Float16* bufB16 = (_Float16*)(ws + 40960 + 13107200); // L1 out f16 HWC
    // L2 out reuses bufA16; L3 out reuses bufB16.

    wnorm_all<<<131, 64, 0, stream>>>(c0v, c0g, c1v, c1g, c2v, c2g, c3v, c3g,
                                      lv, lg, w0, w1, w2, w3, wl);

    // <CIN,H,COUT,CG,WX,SEGS,BDIM,PSB>  grid = B * CGRP * STRIPS
    conv_iaf_pool<2,  64, 8,  4, 32, 1, 256, 8 ><<<1024, 256, 0, stream>>>(x,       w0, bufA16, B, T); // L0
    conv_iaf_pool<8,  32, 16, 4, 32, 1, 256, 16><<<512,  256, 0, stream>>>(bufA16,  w1, bufB16, B, T); // L1
    conv_iaf_pool<16, 16, 32, 4, 16, 1, 256, 48><<<256,  256, 0, stream>>>(bufB16,  w2, bufA16, B, T); // L2
    conv_iaf_pool<32, 8,  64, 2, 8,  2, 128, 80><<<512,  128, 0, stream>>>(bufA16,  w3, bufB16, B, T); // L3

    linear_kernel<<<B * T, 256, 0, stream>>>(bufB16, wl, out);
}

// Round 9
// 627.390 us; speedup vs baseline: 1.2833x; 1.0084x over previous
//
#include <hip/hip_runtime.h>

#define THRESH 0.1f

typedef float    f4 __attribute__((ext_vector_type(4)));
typedef float    f2 __attribute__((ext_vector_type(2)));
typedef _Float16 h8 __attribute__((ext_vector_type(8)));
typedef _Float16 h4 __attribute__((ext_vector_type(4)));
typedef _Float16 h2 __attribute__((ext_vector_type(2)));

// ---------------------------------------------------------------------------
// Merged weight norm (per-row reduction math identical to all prior rounds).
// Linear rows are written PERMUTED to HWC fanin order: dst[pix*64+c]=src[c*16+pix]
// ---------------------------------------------------------------------------
__global__ void wnorm_all(const float* __restrict__ c0v, const float* __restrict__ c0g,
                          const float* __restrict__ c1v, const float* __restrict__ c1g,
                          const float* __restrict__ c2v, const float* __restrict__ c2g,
                          const float* __restrict__ c3v, const float* __restrict__ c3g,
                          const float* __restrict__ lv,  const float* __restrict__ lg,
                          float* __restrict__ w0, float* __restrict__ w1,
                          float* __restrict__ w2, float* __restrict__ w3,
                          float* __restrict__ wl) {
    int rb = blockIdx.x;
    const float *v, *g; float* w; int fanin, row;
    if (rb < 8)        { v = c0v; g = c0g; w = w0; fanin = 18;   row = rb; }
    else if (rb < 24)  { v = c1v; g = c1g; w = w1; fanin = 72;   row = rb - 8; }
    else if (rb < 56)  { v = c2v; g = c2g; w = w2; fanin = 144;  row = rb - 24; }
    else if (rb < 120) { v = c3v; g = c3g; w = w3; fanin = 288;  row = rb - 56; }
    else               { v = lv;  g = lg;  w = wl; fanin = 1024; row = rb - 120; }
    const bool perm = (rb >= 120);

    const float* vr = v + (size_t)row * fanin;
    float ss = 0.f;
    for (int i = threadIdx.x; i < fanin; i += 64) { float x = vr[i]; ss = fmaf(x, x, ss); }
    #pragma unroll
    for (int off = 32; off > 0; off >>= 1) ss += __shfl_down(ss, off);
    ss = __shfl(ss, 0);
    float scale = g[row] / sqrtf(ss);
    float* wr = w + (size_t)row * fanin;
    for (int i = threadIdx.x; i < fanin; i += 64) {
        int d = perm ? (((i & 15) << 6) | (i >> 4)) : i;
        wr[d] = vr[i] * scale;
    }
}

// ---------------------------------------------------------------------------
// Fused conv3x3(SAME) + IAF + 2x2 avgpool.  f16/HWC inter-layer tensors.
// R10 (best, 451.7us): L2/L3 CG doubled (halved LDS read traffic).
// R11/R13/R14 (failed): TP=2 variants -> over the 256 addressable-VGPR cap.
// R12 (failed): rolled o-loop -> serialized (loop boundary = sched fence).
// R15 (failed): full 4-phase hoist = 144 live VGPR -> allocator shuffled
//   through AGPRs / mild spill, serialized worse (233us).
// R16: 2-DEEP PHASE PIPELINE at TP=1. Per unrolled o: loads(o+1); SB(0);
//   fma(o). The scheduler region between SBs = {fma(o-1), loads(o+1)} so
//   loads issue under the previous phase's ~600-cyc fma block and complete
//   a full phase early (counted lgkmcnt). Live = 2x9 h8 = 72 VGPR + ~45
//   overhead -- fits. Same load addresses, same per-acc fma chain
//   (o,cid,k asc) -> bit-exact vs R10.
// ---------------------------------------------------------------------------
template<int CIN, int H, int COUT, int CG, int WX, int SEGS, int BDIM, int PSB>
__launch_bounds__(BDIM)
__global__ void conv_iaf_pool(const void* __restrict__ in_, const float* __restrict__ w,
                              _Float16* __restrict__ out, int B, int T) {
    constexpr bool HIN  = (CIN % 8 == 0);     // f16 HWC input path
    constexpr int Hp    = H / 2;
    constexpr int PP    = Hp * Hp;
    constexpr int HH    = H * H;
    constexpr int WY    = 64 / WX;
    constexpr int NW    = BDIM / 64;
    constexpr int NWps  = NW / SEGS;
    constexpr int XW    = H / WX;             // waves across x (L0: 2, else 1)
    constexpr int YWV   = NWps / XW;
    constexpr int RPB   = YWV * WY;           // conv rows per block
    constexpr int STRIPS= H / RPB;
    constexpr int CGRP  = COUT / (CG * SEGS);
    constexpr int SR    = RPB + 2;
    constexpr int COLS  = H + 2;
    constexpr int SLABB = SR * COLS * PSB;    // slab bytes
    constexpr bool FULLY= (RPB == H);
    constexpr int R0    = FULLY ? 1 : 0;
    constexpr int NR    = FULLY ? H : SR;
    constexpr int UPC   = HIN ? (CIN / 8) : 1;    // staging units per position
    constexpr int NU    = NR * H * UPC;
    constexpr int ITERS = (NU + BDIM - 1) / BDIM;
    constexpr bool GUARD= !(FULLY && (NU % BDIM == 0));

    __shared__ alignas(16) char slab[2][SLABB];

    const int tid = threadIdx.x;
    const int G = gridDim.x, bx = blockIdx.x;
    const int pb = (bx & 7) * (G >> 3) + (bx >> 3);   // XCD clustering
    const int cgb   = pb % CGRP;
    const int strip = (pb / CGRP) % STRIPS;
    const int b     = pb / (CGRP * STRIPS);

    const int wid = tid >> 6, l = tid & 63;
    const int seg = wid / NWps;
    const int wlv = wid % NWps;
    const int xw = wlv % XW, yw = wlv / XW;
    const int xl = l % WX, ylw = l / WX;
    const int x  = xw * WX + xl;
    const int yy = yw * WY + ylw;
    const int y0 = strip * RPB;
    const int y  = y0 + yy;

    const int c0 = __builtin_amdgcn_readfirstlane((cgb * SEGS + seg) * CG);
    const float* __restrict__ wu = w + (size_t)c0 * (CIN * 9);

    // patch base byte offsets
    int addrB[9];
    #pragma unroll
    for (int dr = 0; dr < 3; ++dr)
        #pragma unroll
        for (int dc = 0; dc < 3; ++dc)
            addrB[dr * 3 + dc] = ((yy + dr) * COLS + (x + dc)) * PSB;

    // staging maps (lane-invariant over t)
    int goff[ITERS], loffB[ITERS];
    #pragma unroll
    for (int i = 0; i < ITERS; ++i) {
        const int idx = tid + i * BDIM;
        int j, gx, rr0;
        if constexpr (HIN) { j = idx % UPC; gx = (idx / UPC) % H; rr0 = idx / (UPC * H); }
        else               { j = 0;         gx = idx % H;         rr0 = (idx / H) % NR; }
        const int rr = R0 + rr0;
        const int gy = y0 - 1 + rr;
        const bool ok = (idx < NU) && ((unsigned)gy < (unsigned)H);
        if constexpr (HIN) goff[i] = ok ? ((gy * H + gx) * UPC + j) : -1;
        else               goff[i] = ok ? (gy * H + gx) : -1;
        loffB[i] = ok ? ((rr * COLS + (gx + 1)) * PSB + 16 * j) : -1;
    }

    constexpr bool WREG = !HIN && (CG * CIN * 9) <= 80;   // L0 only
    float wreg[WREG ? (CG * CIN * 9) : 1];
    if constexpr (WREG) {
        #pragma unroll
        for (int i = 0; i < CG * CIN * 9; ++i) wreg[i] = wu[i];
    }

    // zero both slabs (halo rows/cols persist as zeros)
    for (int i = tid; i < (2 * SLABB) / 4; i += BDIM) ((int*)slab)[i] = 0;
    __syncthreads();

    float vmem[CG];
    #pragma unroll
    for (int c = 0; c < CG; ++c) vmem[c] = 0.f;

    f4 pf[ITERS];
    #define GATHER(t_)                                                            \
        if constexpr (HIN) {                                                      \
            const f4* inb = (const f4*)in_ + (size_t)(b * T + (t_)) * (HH * UPC); \
            _Pragma("unroll")                                                     \
            for (int i = 0; i < ITERS; ++i) {                                     \
                f4 r_ = {0.f, 0.f, 0.f, 0.f};                                     \
                if (!GUARD || goff[i] >= 0) r_ = inb[goff[i]];                    \
                pf[i] = r_;                                                       \
            }                                                                     \
        } else {                                                                  \
            const float* inb = (const float*)in_ + (size_t)(b * T + (t_)) * (CIN * HH); \
            _Pragma("unroll")                                                     \
            for (int i = 0; i < ITERS; ++i) {                                     \
                f4 r_ = {0.f, 0.f, 0.f, 0.f};                                     \
                if (goff[i] >= 0) { r_.x = inb[goff[i]]; r_.y = inb[goff[i] + HH]; } \
                pf[i] = r_;                                                       \
            }                                                                     \
        }
    #define STAGE(buf)                                                            \
        _Pragma("unroll")                                                         \
        for (int i = 0; i < ITERS; ++i) {                                         \
            if (!GUARD || loffB[i] >= 0) {                                        \
                if constexpr (HIN) *(f4*)(&slab[buf][loffB[i]]) = pf[i];          \
                else { f2 v2_; v2_.x = pf[i].x; v2_.y = pf[i].y;                  \
                       *(f2*)(&slab[buf][loffB[i]]) = v2_; }                      \
            }                                                                     \
        }

    {   // prologue: stage frame 0, prefetch frame 1
        GATHER(0)
        STAGE(0)
        GATHER(1)
    }
    __syncthreads();

    for (int t = 0; t < T; ++t) {
        if (t + 1 < T) { STAGE((t + 1) & 1) }
        if (t + 2 < T) { GATHER(t + 2) }

        const char* sb = slab[t & 1];
        float acc[CG];
        #pragma unroll
        for (int c = 0; c < CG; ++c) acc[c] = 0.f;

        if constexpr (HIN) {
            constexpr int NO = CIN / 8;
            // R16: 2-deep phase pipeline. loads(o+1) issue under fma(o-1)'s
            // block (scheduler region between consecutive SBs), so each
            // phase's data completes a full phase ahead of its use.
            h8 P[2][9];
            #pragma unroll
            for (int k = 0; k < 9; ++k)
                P[0][k] = *(const h8*)(sb + addrB[k]);
            #pragma unroll
            for (int o = 0; o < NO; ++o) {
                if (o + 1 < NO) {
                    #pragma unroll
                    for (int k = 0; k < 9; ++k)
                        P[(o + 1) & 1][k] = *(const h8*)(sb + addrB[k] + 16 * (o + 1));
                }
                __builtin_amdgcn_sched_barrier(0);   // loads above, fmas below
                #pragma unroll
                for (int cid = 0; cid < 8; ++cid) {
                    const int ci = 8 * o + cid;
                    #pragma unroll
                    for (int c = 0; c < CG; ++c)
                        #pragma unroll
                        for (int k = 0; k < 9; ++k)
                            acc[c] = fmaf((float)P[o & 1][k][cid],
                                          wu[(size_t)(c * CIN + ci) * 9 + k], acc[c]);
                }
            }
        } else {
            f2 P[9];
            #pragma unroll
            for (int k = 0; k < 9; ++k)
                P[k] = *(const f2*)(sb + addrB[k]);
            #pragma unroll
            for (int cid = 0; cid < 2; ++cid)
                #pragma unroll
                for (int c = 0; c < CG; ++c)
                    #pragma unroll
                    for (int k = 0; k < 9; ++k)
                        acc[c] = fmaf(P[k][cid],
                                      WREG ? wreg[(c * CIN + cid) * 9 + k]
                                           : wu[(size_t)(c * CIN + cid) * 9 + k],
                                      acc[c]);
        }

        float sv[CG];
        #pragma unroll
        for (int c = 0; c < CG; ++c) {
            vmem[c] += acc[c];
            float s = (vmem[c] >= THRESH) ? 1.f : 0.f;
            vmem[c] -= THRESH * s;
            float sum = s;                         // exact 0/1 sums
            sum += __shfl_xor(sum, 1);
            sum += __shfl_xor(sum, WX);
            sv[c] = 0.25f * sum;                   // in {0,.25,.5,.75,1} -- exact f16
        }
        if (((xl | ylw) & 1) == 0) {
            const size_t ob = ((size_t)(b * T + t) * PP + (y >> 1) * Hp + (x >> 1)) * COUT + c0;
            if constexpr (CG == 4) {
                h4 hv = {(_Float16)sv[0], (_Float16)sv[1], (_Float16)sv[2], (_Float16)sv[3]};
                *(h4*)(out + ob) = hv;
            } else if constexpr (CG == 2) {
                h2 hv = {(_Float16)sv[0], (_Float16)sv[1]};
                *(h2*)(out + ob) = hv;
            } else {
                out[ob] = (_Float16)sv[0];
            }
        }
        __syncthreads();                           // single barrier per timestep
    }
    #undef GATHER
    #undef STAGE
}

// ---------------------------------------------------------------------------
// Linear: out (1600, 11) = h (1600, 1024 f16 HWC) @ wl_perm^T (11, 1024)
// ---------------------------------------------------------------------------
__global__ void linear_kernel(const _Float16* __restrict__ h, const float* __restrict__ w,
                              float* __restrict__ out) {
    __shared__ float hs[1024];
    __shared__ float part[16][17];
    const int n = blockIdx.x;
    for (int i = threadIdx.x; i < 1024; i += blockDim.x)
        hs[i] = (float)h[(size_t)n * 1024 + i];
    __syncthreads();
    const int j = threadIdx.x & 15, ch = threadIdx.x >> 4;
    float acc = 0.f;
    if (j < 11) {
        const float* wr = w + (size_t)j * 1024 + ch * 64;
        const float* hh = hs + ch * 64;
        #pragma unroll 8
        for (int k = 0; k < 64; ++k) acc = fmaf(hh[k], wr[k], acc);
    }
    part[j][ch] = acc;
    __syncthreads();
    if (threadIdx.x < 11) {
        float s = 0.f;
        #pragma unroll
        for (int cc = 0; cc < 16; ++cc) s += part[threadIdx.x][cc];
        out[(size_t)n * 11 + threadIdx.x] = s;
    }
}

// ---------------------------------------------------------------------------
extern "C" void kernel_launch(void* const* d_in, const int* in_sizes, int n_in,
                              void* d_out, int out_size, void* d_ws, size_t ws_size,
                              hipStream_t stream) {
    const int B = 32, T = 50;

    const float* x   = (const float*)d_in[0];
    const float* c0v = (const float*)d_in[1];
    const float* c0g = (const float*)d_in[2];
    const float* c1v = (const float*)d_in[3];
    const float* c1g = (const float*)d_in[4];
    const float* c2v = (const float*)d_in[5];
    const float* c2g = (const float*)d_in[6];
    const float* c3v = (const float*)d_in[7];
    const float* c3g = (const float*)d_in[8];
    const float* lv  = (const float*)d_in[9];
    const float* lg  = (const float*)d_in[10];
    float* out = (float*)d_out;

    // Workspace layout
    float* ws = (float*)d_ws;
    float* w0 = ws;                    // 8*2*9     = 144
    float* w1 = w0 + 144;              // 16*8*9    = 1152
    float* w2 = w1 + 1152;             // 32*16*9   = 4608
    float* w3 = w2 + 4608;             // 64*32*9   = 18432
    float* wl = w3 + 18432;            // 11*1024   = 11264 (HWC-permuted)
    _Float16* bufA16 = (_Float16*)(ws + 40960);            // L0 out f16 HWC
    _Float16* bufB16 = (_Float16*)(ws + 40960 + 13107200); // L1 out f16 HWC
    // L2 out reuses bufA16; L3 out reuses bufB16.

    wnorm_all<<<131, 64, 0, stream>>>(c0v, c0g, c1v, c1g, c2v, c2g, c3v, c3g,
                                      lv, lg, w0, w1, w2, w3, wl);

    // <CIN,H,COUT,CG,WX,SEGS,BDIM,PSB>  grid = B * CGRP * STRIPS
    conv_iaf_pool<2,  64, 8,  4, 32, 1, 256, 8 ><<<1024, 256, 0, stream>>>(x,       w0, bufA16, B, T); // L0
    conv_iaf_pool<8,  32, 16, 4, 32, 1, 256, 16><<<512,  256, 0, stream>>>(bufA16,  w1, bufB16, B, T); // L1
    conv_iaf_pool<16, 16, 32, 4, 16, 1, 256, 48><<<256,  256, 0, stream>>>(bufB16,  w2, bufA16, B, T); // L2
    conv_iaf_pool<32, 8,  64, 2, 8,  2, 128, 80><<<512,  128, 0, stream>>>(bufA16,  w3, bufB16, B, T); // L3

    linear_kernel<<<B * T, 256, 0, stream>>>(bufB16, wl, out);
}

// Round 10
// 561.871 us; speedup vs baseline: 1.4329x; 1.1166x over previous
//
#include <hip/hip_runtime.h>

#define THRESH 0.1f

typedef float    f4 __attribute__((ext_vector_type(4)));
typedef float    f2 __attribute__((ext_vector_type(2)));
typedef _Float16 h8 __attribute__((ext_vector_type(8)));
typedef _Float16 h4 __attribute__((ext_vector_type(4)));
typedef _Float16 h2 __attribute__((ext_vector_type(2)));

// ---------------------------------------------------------------------------
// Merged weight norm (per-row reduction math identical to all prior rounds).
// Linear rows are written PERMUTED to HWC fanin order: dst[pix*64+c]=src[c*16+pix]
// ---------------------------------------------------------------------------
__global__ void wnorm_all(const float* __restrict__ c0v, const float* __restrict__ c0g,
                          const float* __restrict__ c1v, const float* __restrict__ c1g,
                          const float* __restrict__ c2v, const float* __restrict__ c2g,
                          const float* __restrict__ c3v, const float* __restrict__ c3g,
                          const float* __restrict__ lv,  const float* __restrict__ lg,
                          float* __restrict__ w0, float* __restrict__ w1,
                          float* __restrict__ w2, float* __restrict__ w3,
                          float* __restrict__ wl) {
    int rb = blockIdx.x;
    const float *v, *g; float* w; int fanin, row;
    if (rb < 8)        { v = c0v; g = c0g; w = w0; fanin = 18;   row = rb; }
    else if (rb < 24)  { v = c1v; g = c1g; w = w1; fanin = 72;   row = rb - 8; }
    else if (rb < 56)  { v = c2v; g = c2g; w = w2; fanin = 144;  row = rb - 24; }
    else if (rb < 120) { v = c3v; g = c3g; w = w3; fanin = 288;  row = rb - 56; }
    else               { v = lv;  g = lg;  w = wl; fanin = 1024; row = rb - 120; }
    const bool perm = (rb >= 120);

    const float* vr = v + (size_t)row * fanin;
    float ss = 0.f;
    for (int i = threadIdx.x; i < fanin; i += 64) { float x = vr[i]; ss = fmaf(x, x, ss); }
    #pragma unroll
    for (int off = 32; off > 0; off >>= 1) ss += __shfl_down(ss, off);
    ss = __shfl(ss, 0);
    float scale = g[row] / sqrtf(ss);
    float* wr = w + (size_t)row * fanin;
    for (int i = threadIdx.x; i < fanin; i += 64) {
        int d = perm ? (((i & 15) << 6) | (i >> 4)) : i;
        wr[d] = vr[i] * scale;
    }
}

// ---------------------------------------------------------------------------
// Fused conv3x3(SAME) + IAF + 2x2 avgpool.  f16/HWC inter-layer tensors.
// R10 (best, 451.7us): L2/L3 CG doubled. Conv body below is R10 VERBATIM --
//   R11-R16 proved every source-level schedule intervention (TP=2, hoist,
//   sched_barrier, rolled loops) spills past the 256-VGPR cap or serializes.
// R17: WAVE-PRIVATE SLABS for L2/L3 (BDIM=64, one wave per block). The
//   per-timestep __syncthreads forced a vmcnt(0)+lgkmcnt(0) drain, killing
//   the GATHER(t+2) prefetch every iteration (~200-400cyc L2 latency
//   serialized into each of 50 steps at 1 wave/SIMD). With one wave per
//   block there is NO barrier in the t-loop: the t+2 prefetch stays in
//   flight until its STAGE a full timestep later. Costs 1.5-2x global
//   fetch (HBM at 0.6% -- free). Staged values, read addresses, fma chain
//   and pool shuffles untouched -> bit-exact. L0/L1 unchanged (2-4
//   waves/SIMD, drains hidden by TLP).
// ---------------------------------------------------------------------------
template<int CIN, int H, int COUT, int CG, int WX, int SEGS, int BDIM, int PSB>
__launch_bounds__(BDIM)
__global__ void conv_iaf_pool(const void* __restrict__ in_, const float* __restrict__ w,
                              _Float16* __restrict__ out, int B, int T) {
    constexpr bool HIN  = (CIN % 8 == 0);     // f16 HWC input path
    constexpr int Hp    = H / 2;
    constexpr int PP    = Hp * Hp;
    constexpr int HH    = H * H;
    constexpr int WY    = 64 / WX;
    constexpr int NW    = BDIM / 64;
    constexpr int NWps  = NW / SEGS;
    constexpr int XW    = H / WX;             // waves across x (L0: 2, else 1)
    constexpr int YWV   = NWps / XW;
    constexpr int RPB   = YWV * WY;           // conv rows per block
    constexpr int STRIPS= H / RPB;
    constexpr int CGRP  = COUT / (CG * SEGS);
    constexpr int SR    = RPB + 2;
    constexpr int COLS  = H + 2;
    constexpr int SLABB = SR * COLS * PSB;    // slab bytes
    constexpr bool FULLY= (RPB == H);
    constexpr int R0    = FULLY ? 1 : 0;
    constexpr int NR    = FULLY ? H : SR;
    constexpr int UPC   = HIN ? (CIN / 8) : 1;    // staging units per position
    constexpr int NU    = NR * H * UPC;
    constexpr int ITERS = (NU + BDIM - 1) / BDIM;
    constexpr bool GUARD= !(FULLY && (NU % BDIM == 0));

    __shared__ alignas(16) char slab[2][SLABB];

    const int tid = threadIdx.x;
    const int G = gridDim.x, bx = blockIdx.x;
    const int pb = (bx & 7) * (G >> 3) + (bx >> 3);   // XCD clustering
    const int cgb   = pb % CGRP;
    const int strip = (pb / CGRP) % STRIPS;
    const int b     = pb / (CGRP * STRIPS);

    const int wid = tid >> 6, l = tid & 63;
    const int seg = wid / NWps;
    const int wlv = wid % NWps;
    const int xw = wlv % XW, yw = wlv / XW;
    const int xl = l % WX, ylw = l / WX;
    const int x  = xw * WX + xl;
    const int yy = yw * WY + ylw;
    const int y0 = strip * RPB;
    const int y  = y0 + yy;

    const int c0 = __builtin_amdgcn_readfirstlane((cgb * SEGS + seg) * CG);
    const float* __restrict__ wu = w + (size_t)c0 * (CIN * 9);

    // patch base byte offsets
    int addrB[9];
    #pragma unroll
    for (int dr = 0; dr < 3; ++dr)
        #pragma unroll
        for (int dc = 0; dc < 3; ++dc)
            addrB[dr * 3 + dc] = ((yy + dr) * COLS + (x + dc)) * PSB;

    // staging maps (lane-invariant over t)
    int goff[ITERS], loffB[ITERS];
    #pragma unroll
    for (int i = 0; i < ITERS; ++i) {
        const int idx = tid + i * BDIM;
        int j, gx, rr0;
        if constexpr (HIN) { j = idx % UPC; gx = (idx / UPC) % H; rr0 = idx / (UPC * H); }
        else               { j = 0;         gx = idx % H;         rr0 = (idx / H) % NR; }
        const int rr = R0 + rr0;
        const int gy = y0 - 1 + rr;
        const bool ok = (idx < NU) && ((unsigned)gy < (unsigned)H);
        if constexpr (HIN) goff[i] = ok ? ((gy * H + gx) * UPC + j) : -1;
        else               goff[i] = ok ? (gy * H + gx) : -1;
        loffB[i] = ok ? ((rr * COLS + (gx + 1)) * PSB + 16 * j) : -1;
    }

    constexpr bool WREG = !HIN && (CG * CIN * 9) <= 80;   // L0 only
    float wreg[WREG ? (CG * CIN * 9) : 1];
    if constexpr (WREG) {
        #pragma unroll
        for (int i = 0; i < CG * CIN * 9; ++i) wreg[i] = wu[i];
    }

    // zero both slabs (halo rows/cols persist as zeros)
    for (int i = tid; i < (2 * SLABB) / 4; i += BDIM) ((int*)slab)[i] = 0;
    if constexpr (NW > 1) __syncthreads();

    float vmem[CG];
    #pragma unroll
    for (int c = 0; c < CG; ++c) vmem[c] = 0.f;

    f4 pf[ITERS];
    #define GATHER(t_)                                                            \
        if constexpr (HIN) {                                                      \
            const f4* inb = (const f4*)in_ + (size_t)(b * T + (t_)) * (HH * UPC); \
            _Pragma("unroll")                                                     \
            for (int i = 0; i < ITERS; ++i) {                                     \
                f4 r_ = {0.f, 0.f, 0.f, 0.f};                                     \
                if (!GUARD || goff[i] >= 0) r_ = inb[goff[i]];                    \
                pf[i] = r_;                                                       \
            }                                                                     \
        } else {                                                                  \
            const float* inb = (const float*)in_ + (size_t)(b * T + (t_)) * (CIN * HH); \
            _Pragma("unroll")                                                     \
            for (int i = 0; i < ITERS; ++i) {                                     \
                f4 r_ = {0.f, 0.f, 0.f, 0.f};                                     \
                if (goff[i] >= 0) { r_.x = inb[goff[i]]; r_.y = inb[goff[i] + HH]; } \
                pf[i] = r_;                                                       \
            }                                                                     \
        }
    #define STAGE(buf)                                                            \
        _Pragma("unroll")                                                         \
        for (int i = 0; i < ITERS; ++i) {                                         \
            if (!GUARD || loffB[i] >= 0) {                                        \
                if constexpr (HIN) *(f4*)(&slab[buf][loffB[i]]) = pf[i];          \
                else { f2 v2_; v2_.x = pf[i].x; v2_.y = pf[i].y;                  \
                       *(f2*)(&slab[buf][loffB[i]]) = v2_; }                      \
            }                                                                     \
        }

    {   // prologue: stage frame 0, prefetch frame 1
        GATHER(0)
        STAGE(0)
        GATHER(1)
    }
    if constexpr (NW > 1) __syncthreads();

    for (int t = 0; t < T; ++t) {
        if (t + 1 < T) { STAGE((t + 1) & 1) }
        if (t + 2 < T) { GATHER(t + 2) }

        const char* sb = slab[t & 1];
        float acc[CG];
        #pragma unroll
        for (int c = 0; c < CG; ++c) acc[c] = 0.f;

        if constexpr (HIN) {
            #pragma unroll
            for (int o = 0; o < CIN / 8; ++o) {
                h8 P[9];
                #pragma unroll
                for (int k = 0; k < 9; ++k)
                    P[k] = *(const h8*)(sb + addrB[k] + 16 * o);
                #pragma unroll
                for (int cid = 0; cid < 8; ++cid) {
                    const int ci = 8 * o + cid;
                    #pragma unroll
                    for (int c = 0; c < CG; ++c)
                        #pragma unroll
                        for (int k = 0; k < 9; ++k)
                            acc[c] = fmaf((float)P[k][cid],
                                          wu[(size_t)(c * CIN + ci) * 9 + k], acc[c]);
                }
            }
        } else {
            f2 P[9];
            #pragma unroll
            for (int k = 0; k < 9; ++k)
                P[k] = *(const f2*)(sb + addrB[k]);
            #pragma unroll
            for (int cid = 0; cid < 2; ++cid)
                #pragma unroll
                for (int c = 0; c < CG; ++c)
                    #pragma unroll
                    for (int k = 0; k < 9; ++k)
                        acc[c] = fmaf(P[k][cid],
                                      WREG ? wreg[(c * CIN + cid) * 9 + k]
                                           : wu[(size_t)(c * CIN + cid) * 9 + k],
                                      acc[c]);
        }

        float sv[CG];
        #pragma unroll
        for (int c = 0; c < CG; ++c) {
            vmem[c] += acc[c];
            float s = (vmem[c] >= THRESH) ? 1.f : 0.f;
            vmem[c] -= THRESH * s;
            float sum = s;                         // exact 0/1 sums
            sum += __shfl_xor(sum, 1);
            sum += __shfl_xor(sum, WX);
            sv[c] = 0.25f * sum;                   // in {0,.25,.5,.75,1} -- exact f16
        }
        if (((xl | ylw) & 1) == 0) {
            const size_t ob = ((size_t)(b * T + t) * PP + (y >> 1) * Hp + (x >> 1)) * COUT + c0;
            if constexpr (CG == 4) {
                h4 hv = {(_Float16)sv[0], (_Float16)sv[1], (_Float16)sv[2], (_Float16)sv[3]};
                *(h4*)(out + ob) = hv;
            } else if constexpr (CG == 2) {
                h2 hv = {(_Float16)sv[0], (_Float16)sv[1]};
                *(h2*)(out + ob) = hv;
            } else {
                out[ob] = (_Float16)sv[0];
            }
        }
        if constexpr (NW > 1) __syncthreads();     // barrier only when waves share the slab
    }
    #undef GATHER
    #undef STAGE
}

// ---------------------------------------------------------------------------
// Linear: out (1600, 11) = h (1600, 1024 f16 HWC) @ wl_perm^T (11, 1024)
// ---------------------------------------------------------------------------
__global__ void linear_kernel(const _Float16* __restrict__ h, const float* __restrict__ w,
                              float* __restrict__ out) {
    __shared__ float hs[1024];
    __shared__ float part[16][17];
    const int n = blockIdx.x;
    for (int i = threadIdx.x; i < 1024; i += blockDim.x)
        hs[i] = (float)h[(size_t)n * 1024 + i];
    __syncthreads();
    const int j = threadIdx.x & 15, ch = threadIdx.x >> 4;
    float acc = 0.f;
    if (j < 11) {
        const float* wr = w + (size_t)j * 1024 + ch * 64;
        const float* hh = hs + ch * 64;
        #pragma unroll 8
        for (int k = 0; k < 64; ++k) acc = fmaf(hh[k], wr[k], acc);
    }
    part[j][ch] = acc;
    __syncthreads();
    if (threadIdx.x < 11) {
        float s = 0.f;
        #pragma unroll
        for (int cc = 0; cc < 16; ++cc) s += part[threadIdx.x][cc];
        out[(size_t)n * 11 + threadIdx.x] = s;
    }
}

// ---------------------------------------------------------------------------
extern "C" void kernel_launch(void* const* d_in, const int* in_sizes, int n_in,
                              void* d_out, int out_size, void* d_ws, size_t ws_size,
                              hipStream_t stream) {
    const int B = 32, T = 50;

    const float* x   = (const float*)d_in[0];
    const float* c0v = (const float*)d_in[1];
    const float* c0g = (const float*)d_in[2];
    const float* c1v = (const float*)d_in[3];
    const float* c1g = (const float*)d_in[4];
    const float* c2v = (const float*)d_in[5];
    const float* c2g = (const float*)d_in[6];
    const float* c3v = (const float*)d_in[7];
    const float* c3g = (const float*)d_in[8];
    const float* lv  = (const float*)d_in[9];
    const float* lg  = (const float*)d_in[10];
    float* out = (float*)d_out;

    // Workspace layout
    float* ws = (float*)d_ws;
    float* w0 = ws;                    // 8*2*9     = 144
    float* w1 = w0 + 144;              // 16*8*9    = 1152
    float* w2 = w1 + 1152;             // 32*16*9   = 4608
    float* w3 = w2 + 4608;             // 64*32*9   = 18432
    float* wl = w3 + 18432;            // 11*1024   = 11264 (HWC-permuted)
    _Float16* bufA16 = (_Float16*)(ws + 40960);            // L0 out f16 HWC
    _Float16* bufB16 = (_Float16*)(ws + 40960 + 13107200); // L1 out f16 HWC
    // L2 out reuses bufA16; L3 out reuses bufB16.

    wnorm_all<<<131, 64, 0, stream>>>(c0v, c0g, c1v, c1g, c2v, c2g, c3v, c3g,
                                      lv, lg, w0, w1, w2, w3, wl);

    // <CIN,H,COUT,CG,WX,SEGS,BDIM,PSB>  grid = B * CGRP * STRIPS
    conv_iaf_pool<2,  64, 8,  4, 32, 1, 256, 8 ><<<1024, 256, 0, stream>>>(x,       w0, bufA16, B, T); // L0 (R10)
    conv_iaf_pool<8,  32, 16, 4, 32, 1, 256, 16><<<512,  256, 0, stream>>>(bufA16,  w1, bufB16, B, T); // L1 (R10)
    conv_iaf_pool<16, 16, 32, 4, 16, 1, 64,  48><<<1024, 64,  0, stream>>>(bufB16,  w2, bufA16, B, T); // L2 wave-private
    conv_iaf_pool<32, 8,  64, 2, 8,  1, 64,  80><<<1024, 64,  0, stream>>>(bufA16,  w3, bufB16, B, T); // L3 wave-private

    linear_kernel<<<B * T, 256, 0, stream>>>(bufB16, wl, out);
}